// Round 1
// baseline (338.454 us; speedup 1.0000x reference)
//
#include <hip/hip_runtime.h>

// out[b,n] = sum_e c[b,n,e] * s[b,e]
// B=32, N=D1*D2*D3=8192 (2^13), E=256. One wave (64 lanes) per output:
// lane i handles e in [4i, 4i+4) via float4 -> dot -> wave butterfly reduce.
// Pure HBM-bound: ~269 MB traffic, roofline ~43 us @ 6.3 TB/s.

constexpr int kLogN = 13;          // N = 8192 outputs per batch
constexpr int kF4PerRow = 64;      // E/4 = 64 float4 per (b,n) row

__global__ __launch_bounds__(256) void ctx_seg_score_kernel(
    const float* __restrict__ c,   // [B, N, E]
    const float* __restrict__ s,   // [B, E]
    float* __restrict__ out,       // [B, N]
    int total_outputs)             // B*N = 262144
{
    const int tid  = blockIdx.x * blockDim.x + threadIdx.x;
    const int w    = tid >> 6;     // wave id == output index (b*N + n)
    const int lane = tid & 63;
    if (w >= total_outputs) return;

    const int b = w >> kLogN;      // batch index

    const float4* __restrict__ c4p = reinterpret_cast<const float4*>(c);
    const float4* __restrict__ s4p = reinterpret_cast<const float4*>(s);

    // coalesced: 64 lanes x 16B = 1 KiB contiguous per wave
    const float4 c4 = c4p[(size_t)w * kF4PerRow + lane];
    const float4 s4 = s4p[(size_t)b * kF4PerRow + lane];  // L1/L2-hot, reused N times

    float v = c4.x * s4.x + c4.y * s4.y + c4.z * s4.z + c4.w * s4.w;

    // 64-lane butterfly reduction
    #pragma unroll
    for (int off = 32; off > 0; off >>= 1)
        v += __shfl_xor(v, off, 64);

    if (lane == 0) out[w] = v;
}

extern "C" void kernel_launch(void* const* d_in, const int* in_sizes, int n_in,
                              void* d_out, int out_size, void* d_ws, size_t ws_size,
                              hipStream_t stream) {
    const float* c = (const float*)d_in[0];   // [B, D1, D2, D3, E] = [B, N, E]
    const float* s = (const float*)d_in[1];   // [B, E]
    float* out = (float*)d_out;               // [B, N]

    const int total_outputs = out_size;       // 32 * 8192 = 262144
    const int threads = 256;                  // 4 waves/block
    const int waves_needed = total_outputs;   // one wave per output
    const int blocks = (waves_needed * 64 + threads - 1) / threads;  // 65536

    ctx_seg_score_kernel<<<blocks, threads, 0, stream>>>(c, s, out, total_outputs);
}